// Round 2
// baseline (6703.787 us; speedup 1.0000x reference)
//
#include <hip/hip_runtime.h>
#include <hip/hip_bf16.h>
#include <math.h>

// Problem constants
constexpr int cB = 2, cS = 1024, cH = 2048, cNH = 16, cNKV = 4, cHD = 128;
constexpr int cF = 4096, cE = 8, cT = cB * cS;   // 2048 tokens
constexpr float cEPS = 1e-5f;

// ---------------------------------------------------------------------------
// Block reduction helper (256 threads)
// ---------------------------------------------------------------------------
__device__ __forceinline__ float block_reduce_sum(float v, float* red) {
    int tid = threadIdx.x;
    red[tid] = v;
    __syncthreads();
    for (int s = 128; s > 0; s >>= 1) {
        if (tid < s) red[tid] += red[tid + s];
        __syncthreads();
    }
    float r = red[0];
    __syncthreads();
    return r;
}

// ---------------------------------------------------------------------------
// LayerNorm: one block per token row (H = 2048)
// ---------------------------------------------------------------------------
__global__ __launch_bounds__(256) void ln_kernel(const float* __restrict__ in,
                                                 const float* __restrict__ w,
                                                 const float* __restrict__ b,
                                                 float* __restrict__ out) {
    __shared__ float row[cH];
    __shared__ float red[256];
    int t = blockIdx.x;
    const float* x = in + (size_t)t * cH;
    float s = 0.f;
    for (int i = threadIdx.x; i < cH; i += 256) {
        float v = x[i];
        row[i] = v;
        s += v;
    }
    float mu = block_reduce_sum(s, red) * (1.0f / cH);
    float s2 = 0.f;
    for (int i = threadIdx.x; i < cH; i += 256) {
        float d = row[i] - mu;
        s2 += d * d;
    }
    float var = block_reduce_sum(s2, red) * (1.0f / cH);
    float inv = rsqrtf(var + cEPS);
    for (int i = threadIdx.x; i < cH; i += 256)
        out[(size_t)t * cH + i] = (row[i] - mu) * inv * w[i] + b[i];
}

// ---------------------------------------------------------------------------
// Generic fp32 tiled GEMM: C[M,N] = A[M,K] @ B[K,N] (+bias) (+residual)
// 64x64 tile, 16x16 threads, 4x4 per thread, K-step 16.
// ---------------------------------------------------------------------------
template <bool BIAS, bool RES>
__global__ __launch_bounds__(256) void gemm_kernel(const float* __restrict__ A,
                                                   const float* __restrict__ Bm,
                                                   const float* __restrict__ bias,
                                                   const float* __restrict__ res,
                                                   float* __restrict__ C,
                                                   int M, int N, int K) {
    __shared__ float As[64][17];
    __shared__ float Bs[16][64];
    int tid = threadIdx.y * 16 + threadIdx.x;
    int row0 = blockIdx.y * 64, col0 = blockIdx.x * 64;
    float acc[4][4] = {};
    for (int k0 = 0; k0 < K; k0 += 16) {
#pragma unroll
        for (int i = 0; i < 4; i++) {
            int idx = tid + i * 256;
            int r = idx >> 4, c = idx & 15;
            As[r][c] = A[(size_t)(row0 + r) * K + k0 + c];
        }
#pragma unroll
        for (int i = 0; i < 4; i++) {
            int idx = tid + i * 256;
            int r = idx >> 6, c = idx & 63;
            Bs[r][c] = Bm[(size_t)(k0 + r) * N + col0 + c];
        }
        __syncthreads();
#pragma unroll
        for (int kk = 0; kk < 16; kk++) {
            float a[4], bb[4];
#pragma unroll
            for (int i = 0; i < 4; i++) a[i] = As[threadIdx.y * 4 + i][kk];
#pragma unroll
            for (int j = 0; j < 4; j++) bb[j] = Bs[kk][threadIdx.x * 4 + j];
#pragma unroll
            for (int i = 0; i < 4; i++)
#pragma unroll
                for (int j = 0; j < 4; j++) acc[i][j] += a[i] * bb[j];
        }
        __syncthreads();
    }
#pragma unroll
    for (int i = 0; i < 4; i++) {
        int r = row0 + threadIdx.y * 4 + i;
#pragma unroll
        for (int j = 0; j < 4; j++) {
            int c = col0 + threadIdx.x * 4 + j;
            float v = acc[i][j];
            if (BIAS) v += bias[c];
            if (RES) v += res[(size_t)r * N + c];
            C[(size_t)r * N + c] = v;
        }
    }
}

// ---------------------------------------------------------------------------
// RoPE (non-interleaved / rotate_half). One thread per (b,s,head,freq) pair.
// ---------------------------------------------------------------------------
__global__ __launch_bounds__(256) void rope_kernel(float* __restrict__ buf,
                                                   const int* __restrict__ pos_ids,
                                                   int nheads, int total_pairs) {
    int idx = blockIdx.x * 256 + threadIdx.x;
    if (idx >= total_pairs) return;
    int i = idx & 63;        // frequency index 0..63
    int rest = idx >> 6;     // (b*S+s)*nheads + head
    int bs = rest / nheads;
    float pos = (float)pos_ids[bs];
    // inv_freq = 1e6 ^ (-i/64)  -> exp2(-i/64 * log2(1e6))
    float inv_freq = exp2f(-(float)i * (19.931568569324174f / 64.0f));
    float ang = pos * inv_freq;
    float c = cosf(ang), sn = sinf(ang);
    size_t b0 = (size_t)rest * cHD + i;
    float x0 = buf[b0], x1 = buf[b0 + 64];
    buf[b0]      = x0 * c - x1 * sn;
    buf[b0 + 64] = x1 * c + x0 * sn;
}

// ---------------------------------------------------------------------------
// Attention: one block per (q, head, batch). Two-pass softmax in LDS.
// q: [B,S,NH*HD], k/v: [B,S,NKV*HD]
// ---------------------------------------------------------------------------
__global__ __launch_bounds__(256) void attn_kernel(const float* __restrict__ qbuf,
                                                   const float* __restrict__ kbuf,
                                                   const float* __restrict__ vbuf,
                                                   const int* __restrict__ amask,
                                                   float* __restrict__ o) {
    int qi = blockIdx.x, h = blockIdx.y, b = blockIdx.z;
    int kvh = h >> 2;  // NH/NKV = 4
    __shared__ float qs[cHD];
    __shared__ float sc[cS];
    __shared__ float red[256];
    int tid = threadIdx.x;
    const float* qrow = qbuf + (size_t)(b * cS + qi) * (cNH * cHD) + h * cHD;
    if (tid < cHD) qs[tid] = qrow[tid];
    __syncthreads();
    const float scale = 0.08838834764831845f;  // 1/sqrt(128)
    float pmax = -3.402823466e38f;
    for (int j = tid; j <= qi; j += 256) {
        const float* krow = kbuf + ((size_t)(b * cS + j) * cNKV + kvh) * cHD;
        float s = 0.f;
        for (int d = 0; d < cHD; d++) s += qs[d] * krow[d];
        s *= scale;
        if (amask[b * cS + j] <= 0) s = -3.402823466e38f;
        sc[j] = s;
        pmax = fmaxf(pmax, s);
    }
    red[tid] = pmax;
    __syncthreads();
    for (int st = 128; st > 0; st >>= 1) {
        if (tid < st) red[tid] = fmaxf(red[tid], red[tid + st]);
        __syncthreads();
    }
    float m = red[0];
    __syncthreads();
    float psum = 0.f;
    for (int j = tid; j <= qi; j += 256) {
        float p = expf(sc[j] - m);
        sc[j] = p;
        psum += p;
    }
    red[tid] = psum;
    __syncthreads();
    for (int st = 128; st > 0; st >>= 1) {
        if (tid < st) red[tid] += red[tid + st];
        __syncthreads();
    }
    float denom = red[0];
    __syncthreads();
    if (tid < cHD) {
        float acc = 0.f;
        for (int j = 0; j <= qi; j++)
            acc += sc[j] * vbuf[((size_t)(b * cS + j) * cNKV + kvh) * cHD + tid];
        o[(size_t)(b * cS + qi) * (cNH * cHD) + h * cHD + tid] = acc / denom;
    }
}

// ---------------------------------------------------------------------------
// MoE gate: logits = x2 @ gate_w [T,8]; top-2 + softmax weights; count per exp
// ---------------------------------------------------------------------------
__global__ __launch_bounds__(256) void gate_kernel(const float* __restrict__ x2,
                                                   const float* __restrict__ gw,
                                                   int* __restrict__ top_idx,
                                                   float* __restrict__ top_w,
                                                   int* __restrict__ counts) {
    int t = blockIdx.x, tid = threadIdx.x;
    float acc[cE] = {};
    for (int hh = tid; hh < cH; hh += 256) {
        float xv = x2[(size_t)t * cH + hh];
        const float* g = gw + (size_t)hh * cE;
#pragma unroll
        for (int e = 0; e < cE; e++) acc[e] += xv * g[e];
    }
    __shared__ float red[cE][256];
#pragma unroll
    for (int e = 0; e < cE; e++) red[e][tid] = acc[e];
    __syncthreads();
    for (int st = 128; st > 0; st >>= 1) {
        if (tid < st)
#pragma unroll
            for (int e = 0; e < cE; e++) red[e][tid] += red[e][tid + st];
        __syncthreads();
    }
    if (tid == 0) {
        float v[cE];
#pragma unroll
        for (int e = 0; e < cE; e++) v[e] = red[e][0];
        int i1 = 0;
        for (int e = 1; e < cE; e++)
            if (v[e] > v[i1]) i1 = e;
        int i2 = (i1 == 0) ? 1 : 0;
        for (int e = 0; e < cE; e++)
            if (e != i1 && v[e] > v[i2]) i2 = e;
        float ex = expf(v[i2] - v[i1]);
        float w1v = 1.0f / (1.0f + ex), w2v = ex / (1.0f + ex);
        top_idx[t * 2] = i1;
        top_idx[t * 2 + 1] = i2;
        top_w[t * 2] = w1v;
        top_w[t * 2 + 1] = w2v;
        atomicAdd(&counts[i1], 1);
        atomicAdd(&counts[i2], 1);
    }
}

__global__ void zero_counts_kernel(int* counts) {
    if (threadIdx.x < cE) counts[threadIdx.x] = 0;
}

__global__ void offsets_kernel(const int* __restrict__ counts, int* __restrict__ offs,
                               int* __restrict__ cursor) {
    if (threadIdx.x == 0) {
        int acc = 0;
        for (int e = 0; e < cE; e++) {
            offs[e] = acc;
            acc += counts[e];
            cursor[e] = 0;
        }
        offs[cE] = acc;
    }
}

__global__ __launch_bounds__(256) void scatter_kernel(const int* __restrict__ top_idx,
                                                      const int* __restrict__ offs,
                                                      int* __restrict__ cursor,
                                                      int* __restrict__ perm) {
    int t = blockIdx.x * 256 + threadIdx.x;
    if (t >= cT) return;
    for (int slot = 0; slot < 2; slot++) {
        int e = top_idx[t * 2 + slot];
        int p = atomicAdd(&cursor[e], 1);
        perm[offs[e] + p] = (t << 1) | slot;
    }
}

// ---------------------------------------------------------------------------
// MoE up: act[pos, f] = silu(x2[t] @ w1[e]) * (x2[t] @ w3[e])   (gathered rows)
// Grid: (F/64, T/64, E). Early exit when row tile beyond expert count.
// ---------------------------------------------------------------------------
__global__ __launch_bounds__(256) void moe_up_kernel(const float* __restrict__ x2,
                                                     const float* __restrict__ w1,
                                                     const float* __restrict__ w3,
                                                     const int* __restrict__ perm,
                                                     const int* __restrict__ offs,
                                                     const int* __restrict__ counts,
                                                     float* __restrict__ act) {
    int e = blockIdx.z;
    int cnt = counts[e];
    int rt = blockIdx.y;
    if (rt * 64 >= cnt) return;
    int base = offs[e];
    __shared__ float As[64][17];
    __shared__ float Bs1[16][64];
    __shared__ float Bs3[16][64];
    __shared__ int rowtok[64];
    int tid = threadIdx.y * 16 + threadIdx.x;
    if (tid < 64) {
        int lr = rt * 64 + tid;
        rowtok[tid] = (lr < cnt) ? (perm[base + lr] >> 1) : -1;
    }
    __syncthreads();
    int col0 = blockIdx.x * 64;
    const float* B1 = w1 + (size_t)e * cH * cF;
    const float* B3 = w3 + (size_t)e * cH * cF;
    float acc1[4][4] = {}, acc3[4][4] = {};
    for (int k0 = 0; k0 < cH; k0 += 16) {
#pragma unroll
        for (int i = 0; i < 4; i++) {
            int idx = tid + i * 256;
            int r = idx >> 4, c = idx & 15;
            int tok = rowtok[r];
            As[r][c] = (tok >= 0) ? x2[(size_t)tok * cH + k0 + c] : 0.0f;
        }
#pragma unroll
        for (int i = 0; i < 4; i++) {
            int idx = tid + i * 256;
            int r = idx >> 6, c = idx & 63;
            Bs1[r][c] = B1[(size_t)(k0 + r) * cF + col0 + c];
            Bs3[r][c] = B3[(size_t)(k0 + r) * cF + col0 + c];
        }
        __syncthreads();
#pragma unroll
        for (int kk = 0; kk < 16; kk++) {
            float a[4], b1[4], b3[4];
#pragma unroll
            for (int i = 0; i < 4; i++) a[i] = As[threadIdx.y * 4 + i][kk];
#pragma unroll
            for (int j = 0; j < 4; j++) {
                b1[j] = Bs1[kk][threadIdx.x * 4 + j];
                b3[j] = Bs3[kk][threadIdx.x * 4 + j];
            }
#pragma unroll
            for (int i = 0; i < 4; i++)
#pragma unroll
                for (int j = 0; j < 4; j++) {
                    acc1[i][j] += a[i] * b1[j];
                    acc3[i][j] += a[i] * b3[j];
                }
        }
        __syncthreads();
    }
#pragma unroll
    for (int i = 0; i < 4; i++) {
        int lr = rt * 64 + threadIdx.y * 4 + i;
        if (lr < cnt) {
#pragma unroll
            for (int j = 0; j < 4; j++) {
                float h1 = acc1[i][j], h3 = acc3[i][j];
                float sv = h1 / (1.0f + expf(-h1));  // silu
                act[(size_t)(base + lr) * cF + col0 + threadIdx.x * 4 + j] = sv * h3;
            }
        }
    }
}

// ---------------------------------------------------------------------------
// MoE down: out[t] += w_slot * (act[pos] @ w2[e]).   atomicAdd scatter.
// Grid: (H/64, T/64, E)
// ---------------------------------------------------------------------------
__global__ __launch_bounds__(256) void moe_down_kernel(const float* __restrict__ act,
                                                       const float* __restrict__ w2,
                                                       const int* __restrict__ perm,
                                                       const int* __restrict__ offs,
                                                       const int* __restrict__ counts,
                                                       const float* __restrict__ top_w,
                                                       float* __restrict__ out) {
    int e = blockIdx.z;
    int cnt = counts[e];
    int rt = blockIdx.y;
    if (rt * 64 >= cnt) return;
    int base = offs[e];
    __shared__ float As[64][17];
    __shared__ float Bs[16][64];
    int tid = threadIdx.y * 16 + threadIdx.x;
    int col0 = blockIdx.x * 64;
    const float* Bw = w2 + (size_t)e * cF * cH;
    float acc[4][4] = {};
    for (int k0 = 0; k0 < cF; k0 += 16) {
#pragma unroll
        for (int i = 0; i < 4; i++) {
            int idx = tid + i * 256;
            int r = idx >> 4, c = idx & 15;
            int lr = rt * 64 + r;
            As[r][c] = (lr < cnt) ? act[(size_t)(base + lr) * cF + k0 + c] : 0.0f;
        }
#pragma unroll
        for (int i = 0; i < 4; i++) {
            int idx = tid + i * 256;
            int r = idx >> 6, c = idx & 63;
            Bs[r][c] = Bw[(size_t)(k0 + r) * cH + col0 + c];
        }
        __syncthreads();
#pragma unroll
        for (int kk = 0; kk < 16; kk++) {
            float a[4], bb[4];
#pragma unroll
            for (int i = 0; i < 4; i++) a[i] = As[threadIdx.y * 4 + i][kk];
#pragma unroll
            for (int j = 0; j < 4; j++) bb[j] = Bs[kk][threadIdx.x * 4 + j];
#pragma unroll
            for (int i = 0; i < 4; i++)
#pragma unroll
                for (int j = 0; j < 4; j++) acc[i][j] += a[i] * bb[j];
        }
        __syncthreads();
    }
#pragma unroll
    for (int i = 0; i < 4; i++) {
        int lr = rt * 64 + threadIdx.y * 4 + i;
        if (lr < cnt) {
            int code = perm[base + lr];
            int t = code >> 1;
            float wgt = top_w[code];  // code == t*2 + slot
#pragma unroll
            for (int j = 0; j < 4; j++)
                atomicAdd(&out[(size_t)t * cH + col0 + threadIdx.x * 4 + j],
                          wgt * acc[i][j]);
        }
    }
}

// ---------------------------------------------------------------------------
// Launch
// ---------------------------------------------------------------------------
extern "C" void kernel_launch(void* const* d_in, const int* in_sizes, int n_in,
                              void* d_out, int out_size, void* d_ws, size_t ws_size,
                              hipStream_t stream) {
    const float* hidden = (const float*)d_in[0];
    const int* amask    = (const int*)d_in[1];
    const int* pos_ids  = (const int*)d_in[2];
    const float* ln1w   = (const float*)d_in[3];
    const float* ln1b   = (const float*)d_in[4];
    const float* ln2w   = (const float*)d_in[5];
    const float* ln2b   = (const float*)d_in[6];
    const float* wq     = (const float*)d_in[7];
    const float* bq     = (const float*)d_in[8];
    const float* wk     = (const float*)d_in[9];
    const float* bk     = (const float*)d_in[10];
    const float* wv     = (const float*)d_in[11];
    const float* bv     = (const float*)d_in[12];
    const float* wo     = (const float*)d_in[13];
    const float* bo     = (const float*)d_in[14];
    const float* gw     = (const float*)d_in[15];
    const float* w1     = (const float*)d_in[16];
    const float* w2     = (const float*)d_in[17];
    const float* w3     = (const float*)d_in[18];
    float* out = (float*)d_out;

    // workspace layout
    char* ws = (char*)d_ws;
    float* x = (float*)ws;               ws += (size_t)cT * cH * 4;       // post-LN (reused for x2)
    float* qb = (float*)ws;              ws += (size_t)cT * cNH * cHD * 4;
    float* kb = (float*)ws;              ws += (size_t)cT * cNKV * cHD * 4;
    float* vb = (float*)ws;              ws += (size_t)cT * cNKV * cHD * 4;
    float* attn = (float*)ws;            ws += (size_t)cT * cNH * cHD * 4;
    float* act = (float*)ws;             ws += (size_t)cT * 2 * cF * 4;   // 64 MB
    int* top_idx = (int*)ws;             ws += (size_t)cT * 2 * 4;
    float* top_w = (float*)ws;           ws += (size_t)cT * 2 * 4;
    int* perm = (int*)ws;                ws += (size_t)cT * 2 * 4;
    int* counts = (int*)ws;              ws += 64;
    int* offs = (int*)ws;                ws += 64;
    int* cursor = (int*)ws;              ws += 64;

    dim3 blk2(16, 16);

    // 1. LN1
    ln_kernel<<<dim3(cT), dim3(256), 0, stream>>>(hidden, ln1w, ln1b, x);
    // 2. Q/K/V projections
    gemm_kernel<true, false><<<dim3((cNH * cHD) / 64, cT / 64), blk2, 0, stream>>>(
        x, wq, bq, nullptr, qb, cT, cNH * cHD, cH);
    gemm_kernel<true, false><<<dim3((cNKV * cHD) / 64, cT / 64), blk2, 0, stream>>>(
        x, wk, bk, nullptr, kb, cT, cNKV * cHD, cH);
    gemm_kernel<true, false><<<dim3((cNKV * cHD) / 64, cT / 64), blk2, 0, stream>>>(
        x, wv, bv, nullptr, vb, cT, cNKV * cHD, cH);
    // 3. RoPE on q and k
    {
        int qpairs = cB * cS * cNH * 64;
        rope_kernel<<<dim3((qpairs + 255) / 256), dim3(256), 0, stream>>>(qb, pos_ids, cNH, qpairs);
        int kpairs = cB * cS * cNKV * 64;
        rope_kernel<<<dim3((kpairs + 255) / 256), dim3(256), 0, stream>>>(kb, pos_ids, cNKV, kpairs);
    }
    // 4. Attention
    attn_kernel<<<dim3(cS, cNH, cB), dim3(256), 0, stream>>>(qb, kb, vb, amask, attn);
    // 5. O projection + residual -> out (this is h)
    gemm_kernel<true, true><<<dim3(cH / 64, cT / 64), blk2, 0, stream>>>(
        attn, wo, bo, hidden, out, cT, cH, cNH * cHD);
    // 6. LN2 -> x2 (reuse x)
    ln_kernel<<<dim3(cT), dim3(256), 0, stream>>>(out, ln2w, ln2b, x);
    // 7. Gate + routing
    zero_counts_kernel<<<dim3(1), dim3(64), 0, stream>>>(counts);
    gate_kernel<<<dim3(cT), dim3(256), 0, stream>>>(x, gw, top_idx, top_w, counts);
    offsets_kernel<<<dim3(1), dim3(64), 0, stream>>>(counts, offs, cursor);
    scatter_kernel<<<dim3((cT + 255) / 256), dim3(256), 0, stream>>>(top_idx, offs, cursor, perm);
    // 8. MoE up (w1 & w3 fused) -> act
    moe_up_kernel<<<dim3(cF / 64, cT / 64, cE), blk2, 0, stream>>>(
        x, w1, w3, perm, offs, counts, act);
    // 9. MoE down -> atomic accumulate into out
    moe_down_kernel<<<dim3(cH / 64, cT / 64, cE), blk2, 0, stream>>>(
        act, w2, perm, offs, counts, top_w, out);
}